// Round 11
// baseline (216.996 us; speedup 1.0000x reference)
//
#include <hip/hip_runtime.h>
#include <math.h>

#define NHEADS 8
#define NC 9
#define NHC 72
#define FIN 12
#define WAVES_PER_BLOCK 4
#define ROWW 48         // words/row: 8 heads x 5 words (10 bf16, last padded) + 8 als f32 = 192 B
#define ALS_OFF 40      // word offset of al_s within row
#define BUKSH 6         // bucket = dst >> 6 (64 nodes/bucket)
#define MAXBUK 1600     // supports N <= 102400
#define ABLOCKS 1024    // even-split edge blocks for k_bucketA

__device__ __forceinline__ float lrelu(float v) { return v > 0.f ? v : 0.2f * v; }

// round-to-nearest-even bf16 pack of two floats into one uint (a=low, b=high)
__device__ __forceinline__ unsigned pack_bf16(float a, float b) {
    unsigned ua = __float_as_uint(a); ua += 0x7fffu + ((ua >> 16) & 1u);
    unsigned ub = __float_as_uint(b); ub += 0x7fffu + ((ub >> 16) & 1u);
    return (ua >> 16) | (ub & 0xffff0000u);
}
__device__ __forceinline__ float blo(unsigned w) { return __uint_as_float(w << 16); }
__device__ __forceinline__ float bhi(unsigned w) { return __uint_as_float(w & 0xffff0000u); }

// K1: per-node linear transform -> head-padded bf16 row [8x10 bf16 | 8 als f32].
// Fused tail: bucket histogram of dst (LDS-aggregated).
__global__ void __launch_bounds__(256) k_transform(
    const float* __restrict__ x, const float* __restrict__ W,
    const float* __restrict__ a_src, const float* __restrict__ a_dst,
    unsigned* __restrict__ hrow, float* __restrict__ al_d,
    const int* __restrict__ dst, int* __restrict__ bucket_count,
    int N, int E, int nbuk)
{
    __shared__ float sW[FIN * NHC];
    __shared__ float sas[NHC];
    __shared__ float sad[NHC];
    __shared__ int bcnt[MAXBUK];
    int tid = threadIdx.x;
    for (int i = tid; i < FIN * NHC; i += blockDim.x) sW[i] = W[i];
    if (tid < NHC) { sas[tid] = a_src[tid]; sad[tid] = a_dst[tid]; }
    for (int i = tid; i < nbuk; i += blockDim.x) bcnt[i] = 0;
    __syncthreads();
    int n = blockIdx.x * blockDim.x + tid;
    if (n < N) {
        float xv[FIN];
        const float4* xp = reinterpret_cast<const float4*>(x + (size_t)n * FIN);
        float4 q0 = xp[0], q1 = xp[1], q2 = xp[2];
        xv[0] = q0.x; xv[1] = q0.y; xv[2] = q0.z; xv[3] = q0.w;
        xv[4] = q1.x; xv[5] = q1.y; xv[6] = q1.z; xv[7] = q1.w;
        xv[8] = q2.x; xv[9] = q2.y; xv[10] = q2.z; xv[11] = q2.w;

        float acc[NHC];
        #pragma unroll
        for (int j = 0; j < NHC; ++j) acc[j] = 0.f;
        #pragma unroll
        for (int k = 0; k < FIN; ++k) {
            float xk = xv[k];
            #pragma unroll
            for (int j = 0; j < NHC; ++j) acc[j] = fmaf(xk, sW[k * NHC + j], acc[j]);
        }

        unsigned* rp = hrow + (size_t)n * ROWW;
        #pragma unroll
        for (int hh = 0; hh < NHEADS; ++hh) {
            const float* A = acc + hh * NC;
            rp[5 * hh + 0] = pack_bf16(A[0], A[1]);
            rp[5 * hh + 1] = pack_bf16(A[2], A[3]);
            rp[5 * hh + 2] = pack_bf16(A[4], A[5]);
            rp[5 * hh + 3] = pack_bf16(A[6], A[7]);
            rp[5 * hh + 4] = pack_bf16(A[8], 0.f);
        }

        float* rf = reinterpret_cast<float*>(rp);
        #pragma unroll
        for (int hh = 0; hh < NHEADS; ++hh) {
            float ss = 0.f, dd = 0.f;
            #pragma unroll
            for (int c = 0; c < NC; ++c) {
                ss = fmaf(acc[hh * NC + c], sas[hh * NC + c], ss);
                dd = fmaf(acc[hh * NC + c], sad[hh * NC + c], dd);
            }
            rf[ALS_OFF + hh] = ss;
            al_d[(size_t)n * NHEADS + hh] = dd;
        }
    }
    // fused bucket histogram (LDS-aggregated)
    int stride = gridDim.x * blockDim.x;
    for (int i = blockIdx.x * blockDim.x + tid; i < E; i += stride)
        atomicAdd(&bcnt[dst[i] >> BUKSH], 1);
    __syncthreads();
    for (int i = tid; i < nbuk; i += blockDim.x)
        if (bcnt[i]) atomicAdd(&bucket_count[i], bcnt[i]);
}

// K2: single-block chunked scan of bucket counts -> bucket_base, gcur.
__global__ void __launch_bounds__(256) k_bscan(
    const int* __restrict__ bucket_count, int* __restrict__ bucket_base,
    int* __restrict__ gcur, int* __restrict__ rowptr, int nbuk, int N, int E)
{
    __shared__ int sums[256];
    int t = threadIdx.x;
    int chunk = (nbuk + 255) / 256;
    int start = t * chunk;
    int end = min(nbuk, start + chunk);
    int s = 0;
    for (int i = start; i < end; ++i) s += bucket_count[i];
    sums[t] = s;
    __syncthreads();
    for (int off = 1; off < 256; off <<= 1) {
        int u = (t >= off) ? sums[t - off] : 0;
        __syncthreads();
        sums[t] += u;
        __syncthreads();
    }
    int run = (t == 0) ? 0 : sums[t - 1];
    for (int i = start; i < end; ++i) {
        bucket_base[i] = run;
        gcur[i] = run;
        run += bucket_count[i];
    }
    if (t == 0) { bucket_base[nbuk] = E; rowptr[N] = E; }
}

// K3: even-split coarse scatter into buckets: packed (src | d_local<<24).
__global__ void __launch_bounds__(256) k_bucketA(
    const int* __restrict__ src, const int* __restrict__ dst,
    int* __restrict__ gcur, unsigned* __restrict__ bpair, int E, int nbuk)
{
    __shared__ int cnt[MAXBUK];
    __shared__ int sbase[MAXBUK];
    int t = threadIdx.x;
    for (int i = t; i < nbuk; i += 256) cnt[i] = 0;
    __syncthreads();
    int chunk = (E + ABLOCKS - 1) / ABLOCKS;        // 1563 for E=1.6M
    int base0 = blockIdx.x * chunk;
    int hi = min(E, base0 + chunk);
    const int ITER = 7;                              // ceil(1563/256)
    int rk[ITER], bk[ITER];
    unsigned pk[ITER];
    #pragma unroll
    for (int j = 0; j < ITER; ++j) {
        int i = base0 + j * 256 + t;                 // coalesced
        if (i < hi) {
            int d = dst[i];
            int sg = src[i];
            bk[j] = d >> BUKSH;
            pk[j] = (unsigned)sg | ((unsigned)(d & 63) << 24);
            rk[j] = atomicAdd(&cnt[bk[j]], 1);
        } else bk[j] = -1;
    }
    __syncthreads();
    for (int b = t; b < nbuk; b += 256)
        if (cnt[b]) sbase[b] = atomicAdd(&gcur[b], cnt[b]);
    __syncthreads();
    #pragma unroll
    for (int j = 0; j < ITER; ++j)
        if (bk[j] >= 0) bpair[sbase[bk[j]] + rk[j]] = pk[j];
}

// K4: one block per 64-node bucket: per-node counts -> rowptr (wave-0 shuffle
// scan), then fine scatter. Stores row BYTE OFFSETS (src*192).
__global__ void __launch_bounds__(256) k_bucketB(
    const unsigned* __restrict__ bpair, const int* __restrict__ bucket_base,
    int* __restrict__ rowptr, int* __restrict__ sorted_off, int N)
{
    __shared__ int cnt[64];
    int b = blockIdx.x;
    int t = threadIdx.x;
    int lo = bucket_base[b], hi = bucket_base[b + 1];
    if (t < 64) cnt[t] = 0;
    __syncthreads();
    for (int i = lo + t; i < hi; i += 256)
        atomicAdd(&cnt[bpair[i] >> 24], 1);
    __syncthreads();
    if (t < 64) {                                    // wave 0: shuffle scan
        int v = cnt[t];
        int val = v;
        #pragma unroll
        for (int off = 1; off < 64; off <<= 1) {
            int u = __shfl_up(val, off, 64);
            if (t >= off) val += u;
        }
        int abs0 = lo + val - v;                     // exclusive + base
        int node = (b << BUKSH) + t;
        if (node < N) rowptr[node] = abs0;
        cnt[t] = abs0;                               // repurpose as cursor
    }
    __syncthreads();
    for (int i = lo + t; i < hi; i += 256) {
        unsigned w = bpair[i];
        int pos = atomicAdd(&cnt[w >> 24], 1);
        sorted_off[pos] = (int)((w & 0xFFFFFFu) * (ROWW * 4u));
    }
}

// K5 (R9-exact): one wave per dst node. Softmax: 8x8 (edge,head) lanes via
// LDS-staged offsets. Aggregate: 40 lanes x 1 word, readlane row base.
__global__ void __launch_bounds__(256) k_gat(
    const int* __restrict__ rowptr, const int* __restrict__ sorted_off,
    const unsigned* __restrict__ hrow, const float* __restrict__ al_d,
    const float* __restrict__ bias, float* __restrict__ out, int N)
{
    __shared__ int   s_off[WAVES_PER_BLOCK][64];     // row BYTE offsets
    __shared__ float s_ex[WAVES_PER_BLOCK][64][9];   // [edge][head], pad 8->9
    __shared__ float s_den[WAVES_PER_BLOCK][8];
    __shared__ float s_out[WAVES_PER_BLOCK][NHC];
    __shared__ float s_v[WAVES_PER_BLOCK][NC];

    int wid  = threadIdx.x >> 6;
    int lane = threadIdx.x & 63;
    int n = blockIdx.x * WAVES_PER_BLOCK + wid;
    if (n >= N) return;                         // uniform per wave

    int base  = rowptr[n];
    int total = rowptr[n + 1] - base + 1;       // + implicit self-loop at index total-1

    int g  = lane >> 3;                         // edge-slot group (softmax phase)
    int hh = lane & 7;                          // head (softmax phase)
    float ald_h = al_d[(size_t)n * NHEADS + hh];

    // aggregate mapping: lane L<40 -> head h=L/5, word L (cols h*9+2i, h*9+2i+1)
    bool act40 = lane < 40;
    int h_agg = act40 ? lane / 5 : 0;
    int i_agg = act40 ? lane - h_agg * 5 : 4;
    int widx4 = act40 ? lane * 4 : 0;           // word byte-offset within row
    int c0 = h_agg * NC + 2 * i_agg;
    float accA = 0.f, accB = 0.f;
    float den_part = 0.f;

    const char* hbase = reinterpret_cast<const char*>(hrow);
    int als_boff = (ALS_OFF + hh) * 4;          // byte offset of my head's al_s
    int self_off = n * (ROWW * 4);

    for (int cb = 0; cb < total; cb += 64) {
        int rem = total - cb;
        int clen = rem < 64 ? rem : 64;
        int clenR = (clen + 3) & ~3;            // guard-free round-up (<=64)

        // stage row byte-offsets (j >= total-1 -> self row; safe pad, ex=0)
        int j = cb + lane;
        int off_l = self_off;
        if (j < total - 1) off_l = sorted_off[base + j];
        s_off[wid][lane] = off_l;

        // softmax phase: lane (g,hh) handles local edges lj = k*8+g for head hh
        for (int k = 0; k * 8 < clenR; ++k) {
            int lj = k * 8 + g;
            int off = s_off[wid][lj];
            float als = *reinterpret_cast<const float*>(hbase + off + als_boff);
            float ex = 0.f;
            if (cb + lj < total) ex = __expf(lrelu(als + ald_h));
            s_ex[wid][lj][hh] = ex;
            den_part += ex;
        }

        // aggregate phase: readlane -> uniform row base, 1 ds_read/edge, 2 FMA
        for (int e = 0; e < clenR; e += 4) {
            #pragma unroll
            for (int p = 0; p < 4; ++p) {
                int ee = e + p;
                int off = __builtin_amdgcn_readlane(off_l, ee);   // uniform (SGPR)
                unsigned w = *reinterpret_cast<const unsigned*>(hbase + off + widx4);
                float ex1 = s_ex[wid][ee][h_agg];
                accA = fmaf(ex1, blo(w), accA);
                accB = fmaf(ex1, bhi(w), accB);
            }
        }
    }

    // denominator: 3-shuffle reduce across the 8 g-groups per head
    den_part += __shfl_xor(den_part, 8, 64);
    den_part += __shfl_xor(den_part, 16, 64);
    den_part += __shfl_xor(den_part, 32, 64);
    if (lane < 8) s_den[wid][lane] = den_part;

    if (act40) {
        float inv = 1.f / (s_den[wid][h_agg] + 1e-16f);
        s_out[wid][c0] = accA * inv;
        if (i_agg < 4) s_out[wid][c0 + 1] = accB * inv;
    }

    if (lane < NC) {
        float v = 0.f;
        #pragma unroll
        for (int h = 0; h < NHEADS; ++h) v += s_out[wid][h * NC + lane];
        v = v * (1.f / NHEADS) + bias[lane];
        s_v[wid][lane] = v;
        float mx = -INFINITY;
        #pragma unroll
        for (int c = 0; c < NC; ++c) mx = fmaxf(mx, s_v[wid][c]);
        float sum = 0.f;
        #pragma unroll
        for (int c = 0; c < NC; ++c) sum += __expf(s_v[wid][c] - mx);
        float lse = mx + __logf(sum);
        out[(size_t)n * NC + lane] = s_v[wid][lane] - lse;
    }
}

extern "C" void kernel_launch(void* const* d_in, const int* in_sizes, int n_in,
                              void* d_out, int out_size, void* d_ws, size_t ws_size,
                              hipStream_t stream)
{
    const float* x     = (const float*)d_in[0];
    const int*   ei    = (const int*)d_in[1];
    const float* W     = (const float*)d_in[2];
    const float* a_src = (const float*)d_in[3];
    const float* a_dst = (const float*)d_in[4];
    const float* bias  = (const float*)d_in[5];

    int N = in_sizes[0] / FIN;   // 100000
    int E = in_sizes[1] / 2;     // 1600000
    const int* src = ei;
    const int* dst = ei + E;
    int nbuk = (N + 63) >> BUKSH;   // 1563

    char* ws = (char*)d_ws;
    unsigned* hrow = (unsigned*)ws;     ws += (size_t)N * ROWW * sizeof(unsigned);
    float* al_d = (float*)ws;           ws += (size_t)N * NHEADS * sizeof(float);
    int* rowptr = (int*)ws;             ws += (size_t)(N + 1) * sizeof(int);
    int* bucket_count = (int*)ws;       ws += (size_t)(MAXBUK + 1) * sizeof(int);
    int* bucket_base  = (int*)ws;       ws += (size_t)(MAXBUK + 1) * sizeof(int);
    int* gcur = (int*)ws;               ws += (size_t)MAXBUK * sizeof(int);
    unsigned* bpair = (unsigned*)ws;    ws += (size_t)E * sizeof(unsigned);
    int* sorted_off = (int*)ws;         ws += (size_t)E * sizeof(int);

    hipMemsetAsync(bucket_count, 0, (size_t)(MAXBUK + 1) * sizeof(int), stream);

    int nb_n = (N + 255) / 256;

    k_transform<<<nb_n, 256, 0, stream>>>(x, W, a_src, a_dst, hrow, al_d,
                                          dst, bucket_count, N, E, nbuk);
    k_bscan<<<1, 256, 0, stream>>>(bucket_count, bucket_base, gcur, rowptr,
                                   nbuk, N, E);
    k_bucketA<<<ABLOCKS, 256, 0, stream>>>(src, dst, gcur, bpair, E, nbuk);
    k_bucketB<<<nbuk, 256, 0, stream>>>(bpair, bucket_base, rowptr, sorted_off, N);

    int nb_g = (N + WAVES_PER_BLOCK - 1) / WAVES_PER_BLOCK;
    k_gat<<<nb_g, 256, 0, stream>>>(rowptr, sorted_off, hrow, al_d, bias,
                                    (float*)d_out, N);
}

// Round 12
// 153.213 us; speedup vs baseline: 1.4163x; 1.4163x over previous
//
#include <hip/hip_runtime.h>
#include <math.h>

#define NHEADS 8
#define NC 9
#define NHC 72
#define FIN 12
#define WAVES_PER_BLOCK 4
#define ROWW 48         // words/row: 8 heads x 5 words (10 bf16, last padded) + 8 als f32 = 192 B
#define ALS_OFF 40      // word offset of al_s within row
#define MAXBUK 512      // supports N <= 131072 (bucket = dst >> 8)
#define TILE 4096       // edges per k_bucketA block

__device__ __forceinline__ float lrelu(float v) { return v > 0.f ? v : 0.2f * v; }

// round-to-nearest-even bf16 pack of two floats into one uint (a=low, b=high)
__device__ __forceinline__ unsigned pack_bf16(float a, float b) {
    unsigned ua = __float_as_uint(a); ua += 0x7fffu + ((ua >> 16) & 1u);
    unsigned ub = __float_as_uint(b); ub += 0x7fffu + ((ub >> 16) & 1u);
    return (ua >> 16) | (ub & 0xffff0000u);
}
__device__ __forceinline__ float blo(unsigned w) { return __uint_as_float(w << 16); }
__device__ __forceinline__ float bhi(unsigned w) { return __uint_as_float(w & 0xffff0000u); }

// K1: per-node linear transform, 2 THREADS PER NODE (each owns 4 heads = 36
// cols) -> head-padded bf16 row [8x10 bf16 | 8 als f32]. Fused tail: bucket
// histogram of dst (LDS-aggregated; same 391-block grid as R8 -> 153k merges).
__global__ void __launch_bounds__(512) k_transform(
    const float* __restrict__ x, const float* __restrict__ W,
    const float* __restrict__ a_src, const float* __restrict__ a_dst,
    unsigned* __restrict__ hrow, float* __restrict__ al_d,
    const int* __restrict__ dst, int* __restrict__ bucket_count,
    int N, int E, int nbuk)
{
    __shared__ float sW[FIN * NHC];
    __shared__ float sas[NHC];
    __shared__ float sad[NHC];
    __shared__ int bcnt[MAXBUK];
    int tid = threadIdx.x;
    for (int i = tid; i < FIN * NHC; i += blockDim.x) sW[i] = W[i];
    if (tid < NHC) { sas[tid] = a_src[tid]; sad[tid] = a_dst[tid]; }
    for (int i = tid; i < nbuk; i += blockDim.x) bcnt[i] = 0;
    __syncthreads();
    int gid = blockIdx.x * blockDim.x + tid;
    int n = gid >> 1;
    int q = gid & 1;                 // half: heads 4q..4q+3, cols 36q..36q+35
    if (n < N) {
        float xv[FIN];
        const float4* xp = reinterpret_cast<const float4*>(x + (size_t)n * FIN);
        float4 q0 = xp[0], q1 = xp[1], q2 = xp[2];
        xv[0] = q0.x; xv[1] = q0.y; xv[2] = q0.z; xv[3] = q0.w;
        xv[4] = q1.x; xv[5] = q1.y; xv[6] = q1.z; xv[7] = q1.w;
        xv[8] = q2.x; xv[9] = q2.y; xv[10] = q2.z; xv[11] = q2.w;

        float acc[36];
        #pragma unroll
        for (int j = 0; j < 36; ++j) acc[j] = 0.f;
        const float* Wq = sW + 36 * q;
        #pragma unroll
        for (int k = 0; k < FIN; ++k) {
            float xk = xv[k];
            #pragma unroll
            for (int j = 0; j < 36; ++j) acc[j] = fmaf(xk, Wq[k * NHC + j], acc[j]);
        }

        unsigned* rp = hrow + (size_t)n * ROWW + 20 * q;
        #pragma unroll
        for (int hl = 0; hl < 4; ++hl) {
            const float* A = acc + hl * NC;
            rp[5 * hl + 0] = pack_bf16(A[0], A[1]);
            rp[5 * hl + 1] = pack_bf16(A[2], A[3]);
            rp[5 * hl + 2] = pack_bf16(A[4], A[5]);
            rp[5 * hl + 3] = pack_bf16(A[6], A[7]);
            rp[5 * hl + 4] = pack_bf16(A[8], 0.f);
        }

        float ss[4], dd[4];
        #pragma unroll
        for (int hl = 0; hl < 4; ++hl) {
            const float* As = sas + (4 * q + hl) * NC;
            const float* Ad = sad + (4 * q + hl) * NC;
            float s1 = 0.f, d1 = 0.f;
            #pragma unroll
            for (int c = 0; c < NC; ++c) {
                s1 = fmaf(acc[hl * NC + c], As[c], s1);
                d1 = fmaf(acc[hl * NC + c], Ad[c], d1);
            }
            ss[hl] = s1; dd[hl] = d1;
        }
        float* rf = reinterpret_cast<float*>(hrow + (size_t)n * ROWW);
        *reinterpret_cast<float4*>(rf + ALS_OFF + 4 * q) =
            make_float4(ss[0], ss[1], ss[2], ss[3]);
        *reinterpret_cast<float4*>(al_d + (size_t)n * NHEADS + 4 * q) =
            make_float4(dd[0], dd[1], dd[2], dd[3]);
    }
    // fused bucket histogram (LDS-aggregated)
    int stride = gridDim.x * blockDim.x;
    for (int i = blockIdx.x * blockDim.x + tid; i < E; i += stride)
        atomicAdd(&bcnt[dst[i] >> 8], 1);
    __syncthreads();
    for (int i = tid; i < nbuk; i += blockDim.x)
        if (bcnt[i]) atomicAdd(&bucket_count[i], bcnt[i]);
}

// K2: single-block scan of bucket counts -> bucket_base, gcur; rowptr[N]=E.
__global__ void __launch_bounds__(512) k_bscan(
    const int* __restrict__ bucket_count, int* __restrict__ bucket_base,
    int* __restrict__ gcur, int* __restrict__ rowptr, int nbuk, int N, int E)
{
    __shared__ int s[512];
    int t = threadIdx.x;
    int v = (t < nbuk) ? bucket_count[t] : 0;
    s[t] = v;
    __syncthreads();
    for (int off = 1; off < 512; off <<= 1) {
        int u = (t >= off) ? s[t - off] : 0;
        __syncthreads();
        s[t] += u;
        __syncthreads();
    }
    if (t < nbuk) {
        int ex = s[t] - v;
        bucket_base[t] = ex;
        gcur[t] = ex;
    }
    if (t == 0) { bucket_base[nbuk] = E; rowptr[N] = E; }
}

// K3: coarse scatter into buckets: packed (src | d_local<<24), 4B/edge.
__global__ void __launch_bounds__(256) k_bucketA(
    const int* __restrict__ src, const int* __restrict__ dst,
    int* __restrict__ gcur, unsigned* __restrict__ bpair, int E, int nbuk)
{
    __shared__ int cnt[MAXBUK];
    __shared__ int sbase[MAXBUK];
    int t = threadIdx.x;
    for (int i = t; i < nbuk; i += 256) cnt[i] = 0;
    __syncthreads();
    int base0 = blockIdx.x * TILE;
    int rk[16], bk[16];
    unsigned pk[16];
    #pragma unroll
    for (int j = 0; j < 16; ++j) {
        int i = base0 + j * 256 + t;          // coalesced
        if (i < E) {
            int d = dst[i];
            int sg = src[i];
            bk[j] = d >> 8;
            pk[j] = (unsigned)sg | ((unsigned)(d & 255) << 24);
            rk[j] = atomicAdd(&cnt[bk[j]], 1);
        } else bk[j] = -1;
    }
    __syncthreads();
    for (int b = t; b < nbuk; b += 256)
        if (cnt[b]) sbase[b] = atomicAdd(&gcur[b], cnt[b]);
    __syncthreads();
    #pragma unroll
    for (int j = 0; j < 16; ++j)
        if (bk[j] >= 0) bpair[sbase[bk[j]] + rk[j]] = pk[j];
}

// K4: one 512-thr block per 256-node bucket: count -> wave-0 shuffle scan ->
// rowptr (int4) -> fine scatter. Stores row BYTE OFFSETS (src*192).
__global__ void __launch_bounds__(512) k_bucketB(
    const unsigned* __restrict__ bpair, const int* __restrict__ bucket_base,
    int* __restrict__ rowptr, int* __restrict__ sorted_off, int N)
{
    __shared__ int cnt[256];
    int b = blockIdx.x;
    int t = threadIdx.x;
    int lo = bucket_base[b], hi = bucket_base[b + 1];
    if (t < 256) cnt[t] = 0;
    __syncthreads();
    for (int i = lo + t; i < hi; i += 512)
        atomicAdd(&cnt[bpair[i] >> 24], 1);
    __syncthreads();
    if (t < 64) {                  // one wave: lane owns nodes 4t..4t+3
        int c0 = cnt[4 * t], c1 = cnt[4 * t + 1];
        int c2 = cnt[4 * t + 2], c3 = cnt[4 * t + 3];
        int sgrp = c0 + c1 + c2 + c3;
        int val = sgrp;
        #pragma unroll
        for (int off = 1; off < 64; off <<= 1) {
            int u = __shfl_up(val, off, 64);
            if (t >= off) val += u;
        }
        int a0 = lo + val - sgrp;
        int a1 = a0 + c0, a2 = a1 + c1, a3 = a2 + c2;
        int node0 = (b << 8) + 4 * t;
        if (node0 + 3 < N) {
            *reinterpret_cast<int4*>(rowptr + node0) = make_int4(a0, a1, a2, a3);
        } else {
            if (node0 + 0 < N) rowptr[node0 + 0] = a0;
            if (node0 + 1 < N) rowptr[node0 + 1] = a1;
            if (node0 + 2 < N) rowptr[node0 + 2] = a2;
            if (node0 + 3 < N) rowptr[node0 + 3] = a3;
        }
        cnt[4 * t + 0] = a0;       // repurpose as absolute cursors
        cnt[4 * t + 1] = a1;
        cnt[4 * t + 2] = a2;
        cnt[4 * t + 3] = a3;
    }
    __syncthreads();
    for (int i = lo + t; i < hi; i += 512) {
        unsigned w = bpair[i];
        int pos = atomicAdd(&cnt[w >> 24], 1);
        sorted_off[pos] = (int)((w & 0xFFFFFFu) * (ROWW * 4u));
    }
}

// K5 (R9-exact): one wave per dst node. Softmax: 8x8 (edge,head) lanes via
// LDS-staged offsets. Aggregate: 40 lanes x 1 word, readlane row base.
__global__ void __launch_bounds__(256) k_gat(
    const int* __restrict__ rowptr, const int* __restrict__ sorted_off,
    const unsigned* __restrict__ hrow, const float* __restrict__ al_d,
    const float* __restrict__ bias, float* __restrict__ out, int N)
{
    __shared__ int   s_off[WAVES_PER_BLOCK][64];     // row BYTE offsets
    __shared__ float s_ex[WAVES_PER_BLOCK][64][9];   // [edge][head], pad 8->9
    __shared__ float s_den[WAVES_PER_BLOCK][8];
    __shared__ float s_out[WAVES_PER_BLOCK][NHC];
    __shared__ float s_v[WAVES_PER_BLOCK][NC];

    int wid  = threadIdx.x >> 6;
    int lane = threadIdx.x & 63;
    int n = blockIdx.x * WAVES_PER_BLOCK + wid;
    if (n >= N) return;                         // uniform per wave

    int base  = rowptr[n];
    int total = rowptr[n + 1] - base + 1;       // + implicit self-loop at index total-1

    int g  = lane >> 3;                         // edge-slot group (softmax phase)
    int hh = lane & 7;                          // head (softmax phase)
    float ald_h = al_d[(size_t)n * NHEADS + hh];

    // aggregate mapping: lane L<40 -> head h=L/5, word L (cols h*9+2i, h*9+2i+1)
    bool act40 = lane < 40;
    int h_agg = act40 ? lane / 5 : 0;
    int i_agg = act40 ? lane - h_agg * 5 : 4;
    int widx4 = act40 ? lane * 4 : 0;           // word byte-offset within row
    int c0 = h_agg * NC + 2 * i_agg;
    float accA = 0.f, accB = 0.f;
    float den_part = 0.f;

    const char* hbase = reinterpret_cast<const char*>(hrow);
    int als_boff = (ALS_OFF + hh) * 4;          // byte offset of my head's al_s
    int self_off = n * (ROWW * 4);

    for (int cb = 0; cb < total; cb += 64) {
        int rem = total - cb;
        int clen = rem < 64 ? rem : 64;
        int clenR = (clen + 3) & ~3;            // guard-free round-up (<=64)

        // stage row byte-offsets (j >= total-1 -> self row; safe pad, ex=0)
        int j = cb + lane;
        int off_l = self_off;
        if (j < total - 1) off_l = sorted_off[base + j];
        s_off[wid][lane] = off_l;

        // softmax phase: lane (g,hh) handles local edges lj = k*8+g for head hh
        for (int k = 0; k * 8 < clenR; ++k) {
            int lj = k * 8 + g;
            int off = s_off[wid][lj];
            float als = *reinterpret_cast<const float*>(hbase + off + als_boff);
            float ex = 0.f;
            if (cb + lj < total) ex = __expf(lrelu(als + ald_h));
            s_ex[wid][lj][hh] = ex;
            den_part += ex;
        }

        // aggregate phase: readlane -> uniform row base, 1 ds_read/edge, 2 FMA
        for (int e = 0; e < clenR; e += 4) {
            #pragma unroll
            for (int p = 0; p < 4; ++p) {
                int ee = e + p;
                int off = __builtin_amdgcn_readlane(off_l, ee);   // uniform (SGPR)
                unsigned w = *reinterpret_cast<const unsigned*>(hbase + off + widx4);
                float ex1 = s_ex[wid][ee][h_agg];
                accA = fmaf(ex1, blo(w), accA);
                accB = fmaf(ex1, bhi(w), accB);
            }
        }
    }

    // denominator: 3-shuffle reduce across the 8 g-groups per head
    den_part += __shfl_xor(den_part, 8, 64);
    den_part += __shfl_xor(den_part, 16, 64);
    den_part += __shfl_xor(den_part, 32, 64);
    if (lane < 8) s_den[wid][lane] = den_part;

    if (act40) {
        float inv = 1.f / (s_den[wid][h_agg] + 1e-16f);
        s_out[wid][c0] = accA * inv;
        if (i_agg < 4) s_out[wid][c0 + 1] = accB * inv;
    }

    if (lane < NC) {
        float v = 0.f;
        #pragma unroll
        for (int h = 0; h < NHEADS; ++h) v += s_out[wid][h * NC + lane];
        v = v * (1.f / NHEADS) + bias[lane];
        s_v[wid][lane] = v;
        float mx = -INFINITY;
        #pragma unroll
        for (int c = 0; c < NC; ++c) mx = fmaxf(mx, s_v[wid][c]);
        float sum = 0.f;
        #pragma unroll
        for (int c = 0; c < NC; ++c) sum += __expf(s_v[wid][c] - mx);
        float lse = mx + __logf(sum);
        out[(size_t)n * NC + lane] = s_v[wid][lane] - lse;
    }
}

extern "C" void kernel_launch(void* const* d_in, const int* in_sizes, int n_in,
                              void* d_out, int out_size, void* d_ws, size_t ws_size,
                              hipStream_t stream)
{
    const float* x     = (const float*)d_in[0];
    const int*   ei    = (const int*)d_in[1];
    const float* W     = (const float*)d_in[2];
    const float* a_src = (const float*)d_in[3];
    const float* a_dst = (const float*)d_in[4];
    const float* bias  = (const float*)d_in[5];

    int N = in_sizes[0] / FIN;   // 100000
    int E = in_sizes[1] / 2;     // 1600000
    const int* src = ei;
    const int* dst = ei + E;
    int nbuk = (N + 255) >> 8;   // 391

    char* ws = (char*)d_ws;
    unsigned* hrow = (unsigned*)ws;     ws += (size_t)N * ROWW * sizeof(unsigned);
    float* al_d = (float*)ws;           ws += (size_t)N * NHEADS * sizeof(float);
    int* rowptr = (int*)ws;             ws += (size_t)(N + 1) * sizeof(int);
    int* bucket_count = (int*)ws;       ws += (size_t)(MAXBUK + 1) * sizeof(int);
    int* bucket_base  = (int*)ws;       ws += (size_t)(MAXBUK + 1) * sizeof(int);
    int* gcur = (int*)ws;               ws += (size_t)MAXBUK * sizeof(int);
    unsigned* bpair = (unsigned*)ws;    ws += (size_t)E * sizeof(unsigned);
    int* sorted_off = (int*)ws;         ws += (size_t)E * sizeof(int);

    hipMemsetAsync(bucket_count, 0, (size_t)(MAXBUK + 1) * sizeof(int), stream);

    int nb_t = (2 * N + 511) / 512;      // 391 blocks (2 threads/node)
    int nb_a = (E + TILE - 1) / TILE;    // 391

    k_transform<<<nb_t, 512, 0, stream>>>(x, W, a_src, a_dst, hrow, al_d,
                                          dst, bucket_count, N, E, nbuk);
    k_bscan<<<1, 512, 0, stream>>>(bucket_count, bucket_base, gcur, rowptr,
                                   nbuk, N, E);
    k_bucketA<<<nb_a, 256, 0, stream>>>(src, dst, gcur, bpair, E, nbuk);
    k_bucketB<<<nbuk, 512, 0, stream>>>(bpair, bucket_base, rowptr, sorted_off, N);

    int nb_g = (N + WAVES_PER_BLOCK - 1) / WAVES_PER_BLOCK;
    k_gat<<<nb_g, 256, 0, stream>>>(rowptr, sorted_off, hrow, al_d, bias,
                                    (float*)d_out, N);
}

// Round 13
// 147.515 us; speedup vs baseline: 1.4710x; 1.0386x over previous
//
#include <hip/hip_runtime.h>
#include <math.h>

#define NHEADS 8
#define NC 9
#define NHC 72
#define FIN 12
#define WAVES_PER_BLOCK 4
#define ROWW 48         // words/row: 8 heads x 5 words (10 bf16, last padded) + 8 als f32 = 192 B
#define ALS_OFF 40      // word offset of al_s within row
#define MAXBUK 512      // supports N <= 131072 (bucket = dst >> 8)
#define TILE 8192       // edges per k_bucketA block (512 thr x 16)

__device__ __forceinline__ float lrelu(float v) { return v > 0.f ? v : 0.2f * v; }

// round-to-nearest-even bf16 pack of two floats into one uint (a=low, b=high)
__device__ __forceinline__ unsigned pack_bf16(float a, float b) {
    unsigned ua = __float_as_uint(a); ua += 0x7fffu + ((ua >> 16) & 1u);
    unsigned ub = __float_as_uint(b); ub += 0x7fffu + ((ub >> 16) & 1u);
    return (ua >> 16) | (ub & 0xffff0000u);
}
__device__ __forceinline__ float blo(unsigned w) { return __uint_as_float(w << 16); }
__device__ __forceinline__ float bhi(unsigned w) { return __uint_as_float(w & 0xffff0000u); }

// K1: per-node linear transform, 2 threads/node, explicit b128 LDS reads of W.
// Fused tail: bucket histogram of dst (LDS-aggregated).
__global__ void __launch_bounds__(512) k_transform(
    const float* __restrict__ x, const float* __restrict__ W,
    const float* __restrict__ a_src, const float* __restrict__ a_dst,
    unsigned* __restrict__ hrow, float* __restrict__ al_d,
    const int* __restrict__ dst, int* __restrict__ bucket_count,
    int N, int E, int nbuk)
{
    __shared__ float sW[FIN * NHC];
    __shared__ float sas[NHC];
    __shared__ float sad[NHC];
    __shared__ int bcnt[MAXBUK];
    int tid = threadIdx.x;
    for (int i = tid; i < FIN * NHC; i += blockDim.x) sW[i] = W[i];
    if (tid < NHC) { sas[tid] = a_src[tid]; sad[tid] = a_dst[tid]; }
    for (int i = tid; i < nbuk; i += blockDim.x) bcnt[i] = 0;
    __syncthreads();
    int gid = blockIdx.x * blockDim.x + tid;
    int n = gid >> 1;
    int q = gid & 1;                 // half: heads 4q..4q+3, cols 36q..36q+35
    if (n < N) {
        float xv[FIN];
        const float4* xp = reinterpret_cast<const float4*>(x + (size_t)n * FIN);
        float4 q0 = xp[0], q1 = xp[1], q2 = xp[2];
        xv[0] = q0.x; xv[1] = q0.y; xv[2] = q0.z; xv[3] = q0.w;
        xv[4] = q1.x; xv[5] = q1.y; xv[6] = q1.z; xv[7] = q1.w;
        xv[8] = q2.x; xv[9] = q2.y; xv[10] = q2.z; xv[11] = q2.w;

        float acc[36];
        #pragma unroll
        for (int j = 0; j < 36; ++j) acc[j] = 0.f;
        const float4* sW4 = reinterpret_cast<const float4*>(sW);
        #pragma unroll
        for (int k = 0; k < FIN; ++k) {
            float xk = xv[k];
            int b4 = k * (NHC / 4) + 9 * q;          // float4 index, 16B-aligned
            #pragma unroll
            for (int m = 0; m < 9; ++m) {
                float4 w4 = sW4[b4 + m];
                acc[4 * m + 0] = fmaf(xk, w4.x, acc[4 * m + 0]);
                acc[4 * m + 1] = fmaf(xk, w4.y, acc[4 * m + 1]);
                acc[4 * m + 2] = fmaf(xk, w4.z, acc[4 * m + 2]);
                acc[4 * m + 3] = fmaf(xk, w4.w, acc[4 * m + 3]);
            }
        }

        unsigned* rp = hrow + (size_t)n * ROWW + 20 * q;
        #pragma unroll
        for (int hl = 0; hl < 4; ++hl) {
            const float* A = acc + hl * NC;
            rp[5 * hl + 0] = pack_bf16(A[0], A[1]);
            rp[5 * hl + 1] = pack_bf16(A[2], A[3]);
            rp[5 * hl + 2] = pack_bf16(A[4], A[5]);
            rp[5 * hl + 3] = pack_bf16(A[6], A[7]);
            rp[5 * hl + 4] = pack_bf16(A[8], 0.f);
        }

        float ss[4], dd[4];
        #pragma unroll
        for (int hl = 0; hl < 4; ++hl) {
            const float* As = sas + (4 * q + hl) * NC;
            const float* Ad = sad + (4 * q + hl) * NC;
            float s1 = 0.f, d1 = 0.f;
            #pragma unroll
            for (int c = 0; c < NC; ++c) {
                s1 = fmaf(acc[hl * NC + c], As[c], s1);
                d1 = fmaf(acc[hl * NC + c], Ad[c], d1);
            }
            ss[hl] = s1; dd[hl] = d1;
        }
        float* rf = reinterpret_cast<float*>(hrow + (size_t)n * ROWW);
        *reinterpret_cast<float4*>(rf + ALS_OFF + 4 * q) =
            make_float4(ss[0], ss[1], ss[2], ss[3]);
        *reinterpret_cast<float4*>(al_d + (size_t)n * NHEADS + 4 * q) =
            make_float4(dd[0], dd[1], dd[2], dd[3]);
    }
    // fused bucket histogram (LDS-aggregated)
    int stride = gridDim.x * blockDim.x;
    for (int i = blockIdx.x * blockDim.x + tid; i < E; i += stride)
        atomicAdd(&bcnt[dst[i] >> 8], 1);
    __syncthreads();
    for (int i = tid; i < nbuk; i += blockDim.x)
        if (bcnt[i]) atomicAdd(&bucket_count[i], bcnt[i]);
}

// K2: single-block scan of bucket counts -> bucket_base, gcur; rowptr[N]=E.
__global__ void __launch_bounds__(512) k_bscan(
    const int* __restrict__ bucket_count, int* __restrict__ bucket_base,
    int* __restrict__ gcur, int* __restrict__ rowptr, int nbuk, int N, int E)
{
    __shared__ int s[512];
    int t = threadIdx.x;
    int v = (t < nbuk) ? bucket_count[t] : 0;
    s[t] = v;
    __syncthreads();
    for (int off = 1; off < 512; off <<= 1) {
        int u = (t >= off) ? s[t - off] : 0;
        __syncthreads();
        s[t] += u;
        __syncthreads();
    }
    if (t < nbuk) {
        int ex = s[t] - v;
        bucket_base[t] = ex;
        gcur[t] = ex;
    }
    if (t == 0) { bucket_base[nbuk] = E; rowptr[N] = E; }
}

// K3: coarse scatter into buckets, 512-thr blocks, TILE 8192: packed
// (src | d_local<<24), 4B/edge. 196 blocks -> 77k reservation atomics.
__global__ void __launch_bounds__(512) k_bucketA(
    const int* __restrict__ src, const int* __restrict__ dst,
    int* __restrict__ gcur, unsigned* __restrict__ bpair, int E, int nbuk)
{
    __shared__ int cnt[MAXBUK];
    __shared__ int sbase[MAXBUK];
    int t = threadIdx.x;
    for (int i = t; i < nbuk; i += 512) cnt[i] = 0;
    __syncthreads();
    int base0 = blockIdx.x * TILE;
    int rk[16], bk[16];
    unsigned pk[16];
    #pragma unroll
    for (int j = 0; j < 16; ++j) {
        int i = base0 + j * 512 + t;          // coalesced
        if (i < E) {
            int d = dst[i];
            int sg = src[i];
            bk[j] = d >> 8;
            pk[j] = (unsigned)sg | ((unsigned)(d & 255) << 24);
            rk[j] = atomicAdd(&cnt[bk[j]], 1);
        } else bk[j] = -1;
    }
    __syncthreads();
    for (int b = t; b < nbuk; b += 512)
        if (cnt[b]) sbase[b] = atomicAdd(&gcur[b], cnt[b]);
    __syncthreads();
    #pragma unroll
    for (int j = 0; j < 16; ++j)
        if (bk[j] >= 0) bpair[sbase[bk[j]] + rk[j]] = pk[j];
}

// K4: one 512-thr block per 256-node bucket: count -> wave-0 shuffle scan ->
// rowptr (int4) -> fine scatter. Stores row BYTE OFFSETS (src*192).
__global__ void __launch_bounds__(512) k_bucketB(
    const unsigned* __restrict__ bpair, const int* __restrict__ bucket_base,
    int* __restrict__ rowptr, int* __restrict__ sorted_off, int N)
{
    __shared__ int cnt[256];
    int b = blockIdx.x;
    int t = threadIdx.x;
    int lo = bucket_base[b], hi = bucket_base[b + 1];
    if (t < 256) cnt[t] = 0;
    __syncthreads();
    for (int i = lo + t; i < hi; i += 512)
        atomicAdd(&cnt[bpair[i] >> 24], 1);
    __syncthreads();
    if (t < 64) {                  // one wave: lane owns nodes 4t..4t+3
        int c0 = cnt[4 * t], c1 = cnt[4 * t + 1];
        int c2 = cnt[4 * t + 2], c3 = cnt[4 * t + 3];
        int sgrp = c0 + c1 + c2 + c3;
        int val = sgrp;
        #pragma unroll
        for (int off = 1; off < 64; off <<= 1) {
            int u = __shfl_up(val, off, 64);
            if (t >= off) val += u;
        }
        int a0 = lo + val - sgrp;
        int a1 = a0 + c0, a2 = a1 + c1, a3 = a2 + c2;
        int node0 = (b << 8) + 4 * t;
        if (node0 + 3 < N) {
            *reinterpret_cast<int4*>(rowptr + node0) = make_int4(a0, a1, a2, a3);
        } else {
            if (node0 + 0 < N) rowptr[node0 + 0] = a0;
            if (node0 + 1 < N) rowptr[node0 + 1] = a1;
            if (node0 + 2 < N) rowptr[node0 + 2] = a2;
            if (node0 + 3 < N) rowptr[node0 + 3] = a3;
        }
        cnt[4 * t + 0] = a0;       // repurpose as absolute cursors
        cnt[4 * t + 1] = a1;
        cnt[4 * t + 2] = a2;
        cnt[4 * t + 3] = a3;
    }
    __syncthreads();
    for (int i = lo + t; i < hi; i += 512) {
        unsigned w = bpair[i];
        int pos = atomicAdd(&cnt[w >> 24], 1);
        sorted_off[pos] = (int)((w & 0xFFFFFFu) * (ROWW * 4u));
    }
}

// K5 (R9-exact): one wave per dst node. Softmax: 8x8 (edge,head) lanes via
// LDS-staged offsets. Aggregate: 40 lanes x 1 word, readlane row base.
__global__ void __launch_bounds__(256) k_gat(
    const int* __restrict__ rowptr, const int* __restrict__ sorted_off,
    const unsigned* __restrict__ hrow, const float* __restrict__ al_d,
    const float* __restrict__ bias, float* __restrict__ out, int N)
{
    __shared__ int   s_off[WAVES_PER_BLOCK][64];     // row BYTE offsets
    __shared__ float s_ex[WAVES_PER_BLOCK][64][9];   // [edge][head], pad 8->9
    __shared__ float s_den[WAVES_PER_BLOCK][8];
    __shared__ float s_out[WAVES_PER_BLOCK][NHC];
    __shared__ float s_v[WAVES_PER_BLOCK][NC];

    int wid  = threadIdx.x >> 6;
    int lane = threadIdx.x & 63;
    int n = blockIdx.x * WAVES_PER_BLOCK + wid;
    if (n >= N) return;                         // uniform per wave

    int base  = rowptr[n];
    int total = rowptr[n + 1] - base + 1;       // + implicit self-loop at index total-1

    int g  = lane >> 3;                         // edge-slot group (softmax phase)
    int hh = lane & 7;                          // head (softmax phase)
    float ald_h = al_d[(size_t)n * NHEADS + hh];

    // aggregate mapping: lane L<40 -> head h=L/5, word L (cols h*9+2i, h*9+2i+1)
    bool act40 = lane < 40;
    int h_agg = act40 ? lane / 5 : 0;
    int i_agg = act40 ? lane - h_agg * 5 : 4;
    int widx4 = act40 ? lane * 4 : 0;           // word byte-offset within row
    int c0 = h_agg * NC + 2 * i_agg;
    float accA = 0.f, accB = 0.f;
    float den_part = 0.f;

    const char* hbase = reinterpret_cast<const char*>(hrow);
    int als_boff = (ALS_OFF + hh) * 4;          // byte offset of my head's al_s
    int self_off = n * (ROWW * 4);

    for (int cb = 0; cb < total; cb += 64) {
        int rem = total - cb;
        int clen = rem < 64 ? rem : 64;
        int clenR = (clen + 3) & ~3;            // guard-free round-up (<=64)

        // stage row byte-offsets (j >= total-1 -> self row; safe pad, ex=0)
        int j = cb + lane;
        int off_l = self_off;
        if (j < total - 1) off_l = sorted_off[base + j];
        s_off[wid][lane] = off_l;

        // softmax phase: lane (g,hh) handles local edges lj = k*8+g for head hh
        for (int k = 0; k * 8 < clenR; ++k) {
            int lj = k * 8 + g;
            int off = s_off[wid][lj];
            float als = *reinterpret_cast<const float*>(hbase + off + als_boff);
            float ex = 0.f;
            if (cb + lj < total) ex = __expf(lrelu(als + ald_h));
            s_ex[wid][lj][hh] = ex;
            den_part += ex;
        }

        // aggregate phase: readlane -> uniform row base, 1 ds_read/edge, 2 FMA
        for (int e = 0; e < clenR; e += 4) {
            #pragma unroll
            for (int p = 0; p < 4; ++p) {
                int ee = e + p;
                int off = __builtin_amdgcn_readlane(off_l, ee);   // uniform (SGPR)
                unsigned w = *reinterpret_cast<const unsigned*>(hbase + off + widx4);
                float ex1 = s_ex[wid][ee][h_agg];
                accA = fmaf(ex1, blo(w), accA);
                accB = fmaf(ex1, bhi(w), accB);
            }
        }
    }

    // denominator: 3-shuffle reduce across the 8 g-groups per head
    den_part += __shfl_xor(den_part, 8, 64);
    den_part += __shfl_xor(den_part, 16, 64);
    den_part += __shfl_xor(den_part, 32, 64);
    if (lane < 8) s_den[wid][lane] = den_part;

    if (act40) {
        float inv = 1.f / (s_den[wid][h_agg] + 1e-16f);
        s_out[wid][c0] = accA * inv;
        if (i_agg < 4) s_out[wid][c0 + 1] = accB * inv;
    }

    if (lane < NC) {
        float v = 0.f;
        #pragma unroll
        for (int h = 0; h < NHEADS; ++h) v += s_out[wid][h * NC + lane];
        v = v * (1.f / NHEADS) + bias[lane];
        s_v[wid][lane] = v;
        float mx = -INFINITY;
        #pragma unroll
        for (int c = 0; c < NC; ++c) mx = fmaxf(mx, s_v[wid][c]);
        float sum = 0.f;
        #pragma unroll
        for (int c = 0; c < NC; ++c) sum += __expf(s_v[wid][c] - mx);
        float lse = mx + __logf(sum);
        out[(size_t)n * NC + lane] = s_v[wid][lane] - lse;
    }
}

extern "C" void kernel_launch(void* const* d_in, const int* in_sizes, int n_in,
                              void* d_out, int out_size, void* d_ws, size_t ws_size,
                              hipStream_t stream)
{
    const float* x     = (const float*)d_in[0];
    const int*   ei    = (const int*)d_in[1];
    const float* W     = (const float*)d_in[2];
    const float* a_src = (const float*)d_in[3];
    const float* a_dst = (const float*)d_in[4];
    const float* bias  = (const float*)d_in[5];

    int N = in_sizes[0] / FIN;   // 100000
    int E = in_sizes[1] / 2;     // 1600000
    const int* src = ei;
    const int* dst = ei + E;
    int nbuk = (N + 255) >> 8;   // 391

    char* ws = (char*)d_ws;
    unsigned* hrow = (unsigned*)ws;     ws += (size_t)N * ROWW * sizeof(unsigned);
    float* al_d = (float*)ws;           ws += (size_t)N * NHEADS * sizeof(float);
    int* rowptr = (int*)ws;             ws += (size_t)(N + 1) * sizeof(int);
    int* bucket_count = (int*)ws;       ws += (size_t)(MAXBUK + 1) * sizeof(int);
    int* bucket_base  = (int*)ws;       ws += (size_t)(MAXBUK + 1) * sizeof(int);
    int* gcur = (int*)ws;               ws += (size_t)MAXBUK * sizeof(int);
    unsigned* bpair = (unsigned*)ws;    ws += (size_t)E * sizeof(unsigned);
    int* sorted_off = (int*)ws;         ws += (size_t)E * sizeof(int);

    hipMemsetAsync(bucket_count, 0, (size_t)(MAXBUK + 1) * sizeof(int), stream);

    int nb_t = (2 * N + 511) / 512;      // 391 blocks (2 threads/node)
    int nb_a = (E + TILE - 1) / TILE;    // 196

    k_transform<<<nb_t, 512, 0, stream>>>(x, W, a_src, a_dst, hrow, al_d,
                                          dst, bucket_count, N, E, nbuk);
    k_bscan<<<1, 512, 0, stream>>>(bucket_count, bucket_base, gcur, rowptr,
                                   nbuk, N, E);
    k_bucketA<<<nb_a, 512, 0, stream>>>(src, dst, gcur, bpair, E, nbuk);
    k_bucketB<<<nbuk, 512, 0, stream>>>(bpair, bucket_base, rowptr, sorted_off, N);

    int nb_g = (N + WAVES_PER_BLOCK - 1) / WAVES_PER_BLOCK;
    k_gat<<<nb_g, 256, 0, stream>>>(rowptr, sorted_off, hrow, al_d, bias,
                                    (float*)d_out, N);
}